// Round 5
// baseline (346.106 us; speedup 1.0000x reference)
//
#include <hip/hip_runtime.h>
#include <hip/hip_bf16.h>
#include <math.h>

#define B_  512
#define I_  8
#define C_  1152
#define J_  10
#define S_  16
#define K1  9216
#define NKB 288     // sgemm K-blocks (K=9216/32)
#define KBT 16      // tgemm K-blocks (K=512/32)

typedef short short8 __attribute__((ext_vector_type(8)));
typedef float floatx4 __attribute__((ext_vector_type(4)));

__device__ inline unsigned short f2bf(float f) {
    unsigned int u = __float_as_uint(f);
    return (unsigned short)((u + 0x7FFFu + ((u >> 16) & 1u)) >> 16);
}
__device__ inline unsigned int pack2(float a, float b) {
    __hip_bfloat162 h = __float22bfloat162_rn(float2{a, b});
    return *reinterpret_cast<unsigned int*>(&h);
}

// ---------------------------------------------------------------------------
// Grid barrier (R2-validated protocol): release fetch_add (wbl2) + RELAXED
// spin + ONE acquire fence after exit. Non-participants arrive-and-exit.
// Co-residency guaranteed by __launch_bounds__(512,8) => VGPR<=64 => 4
// blocks/CU => capacity 1024 >= 721/720 grid. Monotone counter, no reset.
__device__ __forceinline__ void barrier_arrive_wait(int* bar, int target, bool wait) {
    __syncthreads();
    if (threadIdx.x == 0) {
        __hip_atomic_fetch_add(bar, 1, __ATOMIC_RELEASE, __HIP_MEMORY_SCOPE_AGENT);
        if (wait) {
            while (__hip_atomic_load(bar, __ATOMIC_RELAXED, __HIP_MEMORY_SCOPE_AGENT) < target)
                __builtin_amdgcn_s_sleep(8);
            __threadfence();   // single acquire: invalidate stale L1/L2 once
        }
    }
    __syncthreads();
}

// ---------------------------------------------------------------------------
// SGEMM body + fused fold + reduce + squash. Runs on blocks 0..319.
// XCD-aware decode: each XCD owns 8 nt x 5 j (Bs 2.36MB + Wf 1.48MB in L2).
// Epilogue parallelized: 256 threads (bl,s) + 16-lane shfl_xor msq reduce
// (was a serial 16-thread tail doing 128 LDS reads each).
// MODE 0: uniform cnorm=0.1; MODE 1: softmax fold -> Vf; MODE 2: fold -> out.
template<int MODE>
__device__ __forceinline__ void sgemm_body(float* smf,
        const short8* __restrict__ Wf, const short8* __restrict__ Bs,
        const float* __restrict__ b_ij, unsigned short* __restrict__ Vf,
        float* __restrict__ out, int bid) {
    const int t = threadIdx.x, w = t >> 6, L = t & 63, quad = L >> 4;
    const int xcd = bid & 7, sl = bid >> 3;     // sl in [0,40)
    const int j  = 5 * (xcd >> 2) + sl % 5;     // 0..9
    const int nt = 8 * (xcd & 3) + sl / 5;      // 16-b tile, 0..31

    if (MODE) {
        for (int c = t; c < C_; c += 512) {
            float bv[J_], mx = -1e30f;
            #pragma unroll
            for (int jj = 0; jj < J_; jj++) {
                bv[jj] = b_ij[c * J_ + jj]; mx = fmaxf(mx, bv[jj]);
            }
            float sum = 0.0f;
            #pragma unroll
            for (int jj = 0; jj < J_; jj++) sum += __expf(bv[jj] - mx);
            smf[c] = __expf(bv[j] - mx) / sum;
        }
    }
    __syncthreads();

    const short8* pA = Wf + ((size_t)j * NKB + w * 36) * 64 + L;
    const short8* pB = Bs + ((size_t)nt * NKB + w * 36) * 64 + L;
    floatx4 acc = {0.f, 0.f, 0.f, 0.f};
    if (MODE) {
        #pragma unroll 6
        for (int i = 0; i < 36; i++) {
            short8 a = pA[i * 64];
            const int cb = i * 32 + quad * 8;     // (w*36*32) % 1152 == 0
            float4 cl = *(const float4*)&smf[cb];
            float4 ch = *(const float4*)&smf[cb + 4];
            float cn8[8] = {cl.x, cl.y, cl.z, cl.w, ch.x, ch.y, ch.z, ch.w};
            unsigned int* au = (unsigned int*)&a;
            short8 a2; unsigned int* ao = (unsigned int*)&a2;
            #pragma unroll
            for (int h = 0; h < 4; h++) {
                float f0 = __uint_as_float(au[h] << 16)         * cn8[2 * h];
                float f1 = __uint_as_float(au[h] & 0xffff0000u) * cn8[2 * h + 1];
                ao[h] = pack2(f0, f1);
            }
            acc = __builtin_amdgcn_mfma_f32_16x16x32_bf16(a2, pB[i * 64], acc, 0, 0, 0);
        }
    } else {
        #pragma unroll 6
        for (int i = 0; i < 36; i++)
            acc = __builtin_amdgcn_mfma_f32_16x16x32_bf16(pA[i * 64], pB[i * 64], acc, 0, 0, 0);
    }

    const int col = L & 15, rw = quad << 2;
    float* base = &smf[1152 + w * 256];
    #pragma unroll
    for (int r = 0; r < 4; r++)
        base[(rw + r) * 16 + col] = acc[r];
    __syncthreads();

    if (t < 256) {                       // parallel reduce + squash
        const int bl = t >> 4, s = t & 15;   // 16-lane group shares bl
        float a = 0.f;
        #pragma unroll
        for (int w8 = 0; w8 < 8; w8++)
            a += smf[1152 + w8 * 256 + s * 16 + bl];
        if (MODE == 0) a *= 0.1f;
        float msq = a * a;
        #pragma unroll
        for (int m = 1; m < 16; m <<= 1) msq += __shfl_xor(msq, m);
        const float scale = msq / ((1.f + msq) * sqrtf(msq));
        const float sv = a * scale;
        const int b = nt * 16 + bl;      // global b (0..511)
        if (MODE < 2) {
            const int kb = b >> 5, lh = (b >> 3) & 3, e = b & 7;
            Vf[((size_t)(j * KBT + kb) * 64 + (s | (lh << 4))) * 8 + e] = f2bf(sv);
        } else {
            out[((size_t)b * J_ + j) * S_ + s] = sv;
        }
    }
}

// ---------------------------------------------------------------------------
// D1: PACK (721 blocks, native grid, one task each) -> barrier -> SGEMM<0>
// on blocks 0..319. Blocks >=320 arrive-and-exit.
__global__ __launch_bounds__(512, 8) void k_pack_s0(const float* __restrict__ x,
        const float* __restrict__ W, float* __restrict__ ws,
        float* __restrict__ out, int* __restrict__ bar) {
    __shared__ float lds[10240];
    float* Bs_f = ws;
    float* Bt_f = Bs_f + 2359296;
    float* Wf_f = Bt_f + 2359296;
    float* W2_f = Wf_f + 737280;
    float* Vf_f = W2_f + 737280;
    float* bij  = Vf_f + 40960;
    uint4* Bs = (uint4*)Bs_f;
    uint4* Bt = (uint4*)Bt_f;
    uint4* Wf = (uint4*)Wf_f;
    unsigned short* W2 = (unsigned short*)W2_f;

    const int task = blockIdx.x;
    const int t = threadIdx.x;
    const int w = t >> 6, L = t & 63, quad = L >> 4;

    if (task < 576) {                       // ---- x tile -> Bs + Bt
        const int bt = task / 36, kt = task % 36;
        const int b0 = bt * 32, k0 = kt * 256;
        #pragma unroll
        for (int p = 0; p < 4; p++) {
            int f4 = p * 512 + t;
            int row = f4 >> 6, c4 = (f4 & 63) << 2;
            *(float4*)&lds[row * 260 + c4] =
                *(const float4*)&x[(size_t)(b0 + row) * K1 + k0 + c4];
        }
        __syncthreads();
        #pragma unroll
        for (int p = 0; p < 2; p++) {
            const int bl = p * 16 + (L & 15);
            const float* s = &lds[bl * 260 + w * 32 + quad * 8];
            uint4 o;
            o.x = pack2(s[0], s[1]); o.y = pack2(s[2], s[3]);
            o.z = pack2(s[4], s[5]); o.w = pack2(s[6], s[7]);
            Bs[((size_t)(bt * 2 + p) * NKB + kt * 8 + w) * 64 + L] = o;
        }
        #pragma unroll
        for (int p = 0; p < 2; p++) {
            const int ntl = w * 2 + p;
            const int nl = ntl * 16 + (L & 15);
            float v[8];
            #pragma unroll
            for (int e = 0; e < 8; e++) v[e] = lds[(quad * 8 + e) * 260 + nl];
            uint4 o;
            o.x = pack2(v[0], v[1]); o.y = pack2(v[2], v[3]);
            o.z = pack2(v[4], v[5]); o.w = pack2(v[6], v[7]);
            Bt[((size_t)(kt * 16 + ntl) * KBT + bt) * 64 + L] = o;
        }
    } else if (task < 720) {                // ---- W chunk -> Wf + W2
        const int c0 = (task - 576) * 8;
        #pragma unroll
        for (int p = 0; p < 5; p++) {
            int f4 = p * 512 + t;
            int cc = f4 / 320, off4 = (f4 % 320) << 2;
            *(float4*)&lds[cc * 1280 + off4] =
                *(const float4*)&W[(size_t)(c0 + cc) * 1280 + off4];
        }
        __syncthreads();
        #pragma unroll
        for (int p = 0; p < 3; p++) {
            int o = p * 512 + t;
            if (o < 1280) {
                int j = o >> 7, i = (o >> 4) & 7, m = o & 15;
                int k0w = i * C_ + c0;
                int Lw = m | (((k0w >> 3) & 3) << 4);
                float v[8];
                #pragma unroll
                for (int e = 0; e < 8; e++)
                    v[e] = lds[e * 1280 + j * 128 + m * 8 + i];
                uint4 og;
                og.x = pack2(v[0], v[1]); og.y = pack2(v[2], v[3]);
                og.z = pack2(v[4], v[5]); og.w = pack2(v[6], v[7]);
                Wf[((size_t)j * NKB + (k0w >> 5)) * 64 + Lw] = og;
            }
        }
        #pragma unroll
        for (int p = 0; p < 2; p++) {
            int o = p * 512 + t;
            if (o < 640) {
                int j = o >> 6, i = (o >> 3) & 7, cc = o & 7;
                unsigned int r8[8];
                #pragma unroll
                for (int h = 0; h < 8; h++)
                    r8[h] = pack2(lds[cc * 1280 + j * 128 + (2 * h) * 8 + i],
                                  lds[cc * 1280 + j * 128 + (2 * h + 1) * 8 + i]);
                unsigned short* dst = W2 + ((size_t)(j * 8 + i) * C_ + c0 + cc) * 16;
                *(uint4*)dst       = make_uint4(r8[0], r8[1], r8[2], r8[3]);
                *(uint4*)(dst + 8) = make_uint4(r8[4], r8[5], r8[6], r8[7]);
            }
        }
    } else {                                // ---- zero b_ij
        for (int idx = t; idx < C_ * J_; idx += 512) bij[idx] = 0.0f;
    }

    const bool part = blockIdx.x < 320;
    barrier_arrive_wait(bar, 721, part);
    if (!part) return;

    sgemm_body<0>(lds, (const short8*)Wf_f, (const short8*)Bs_f, bij,
                  (unsigned short*)Vf_f, out, blockIdx.x);
}

// ---------------------------------------------------------------------------
// D2/D3: TGEMM (720 blocks, native grid, atomic-free cumulative b_ij RMW)
// -> barrier -> SGEMM<MODE> on blocks 0..319.
// tgemm: wave w owns i = w (nt = w*72 + cblk); exactly one block per (c,j)
// cell makes the non-atomic b_ij read-add-store race-free. XCD decode:
// each XCD owns 9 cblk x 10 j (Bt 1.15MB + Vf 164KB in its L2).
template<int MODE>
__global__ __launch_bounds__(512, 8) void k_t_s(float* __restrict__ ws,
        float* __restrict__ out, int* __restrict__ bar) {
    __shared__ float lds[3200];          // tgemm red (128) / sgemm smf (3200)
    float* Bs_f = ws;
    float* Bt_f = Bs_f + 2359296;
    float* Wf_f = Bt_f + 2359296;
    float* W2_f = Wf_f + 737280;
    float* Vf_f = W2_f + 737280;
    float* bij  = Vf_f + 40960;
    const short8* Vf = (const short8*)Vf_f;
    const short8* Bt = (const short8*)Bt_f;
    const unsigned short* W2 = (const unsigned short*)W2_f;

    float (*red)[16] = (float(*)[16])lds;
    const int t = threadIdx.x, w = t >> 6, L = t & 63;
    const int bid = blockIdx.x;
    {
        const int xcd = bid & 7, sl = bid >> 3;      // sl in [0,90)
        const int cblk = 9 * xcd + sl / 10;          // 0..71
        const int j    = sl % 10;                    // 0..9
        const int nt   = w * 72 + cblk;              // wave w handles i = w
        const short8* pA = Vf + (size_t)j * KBT * 64 + L;
        const short8* pB = Bt + (size_t)nt * KBT * 64 + L;
        floatx4 a = {0.f, 0.f, 0.f, 0.f};
        #pragma unroll
        for (int kb = 0; kb < KBT; kb++)
            a = __builtin_amdgcn_mfma_f32_16x16x32_bf16(pA[kb * 64], pB[kb * 64], a, 0, 0, 0);
        const int col = L & 15, rw = (L >> 4) << 2;
        const int c = cblk * 16 + col;
        const unsigned short* wp = W2 + ((size_t)(j * 8 + w) * C_ + c) * 16 + rw;
        uint2 wv = *(const uint2*)wp;
        float p = a[0] * __uint_as_float((unsigned int)wv.x << 16)
                + a[1] * __uint_as_float(wv.x & 0xffff0000u)
                + a[2] * __uint_as_float((unsigned int)wv.y << 16)
                + a[3] * __uint_as_float(wv.y & 0xffff0000u);
        p += __shfl_xor(p, 16);          // sum s-quads across the wave
        p += __shfl_xor(p, 32);
        if ((L >> 4) == 0) red[w][col] = p;
        __syncthreads();
        if (t < 16) {
            float acc = 0.f;
            #pragma unroll
            for (int w8 = 0; w8 < 8; w8++) acc += red[w8][t];
            const size_t idx = (size_t)(cblk * 16 + t) * J_ + j;
            bij[idx] += acc * (1.0f / 512.f);   // CUMULATIVE (ref semantics)
        }
    }

    const bool part = bid < 320;
    barrier_arrive_wait(bar, 720, part);
    if (!part) return;

    sgemm_body<MODE>(lds, (const short8*)Wf_f, (const short8*)Bs_f, bij,
                     (unsigned short*)Vf_f, out, bid);
}

// ---------------------------------------------------------------------------
extern "C" void kernel_launch(void* const* d_in, const int* in_sizes, int n_in,
                              void* d_out, int out_size, void* d_ws, size_t ws_size,
                              hipStream_t stream) {
    const float* x = (const float*)d_in[0];   // [512][8][1152]
    const float* W = (const float*)d_in[1];   // [1152][10][16][8]
    float* out = (float*)d_out;               // [512][10][16][1]
    float* ws  = (float*)d_ws;

    // barrier counters past bij (ws poisoned by harness -> memset first)
    int* bar = (int*)(ws + 2359296 * 2 + 737280 * 2 + 40960 + 11520);
    hipMemsetAsync(bar, 0, 256, stream);

    k_pack_s0<<<721, 512, 0, stream>>>(x, W, ws, out, bar);     // pack | s0
    k_t_s<1><<<720, 512, 0, stream>>>(ws, out, bar + 1);        // t0 | s1
    k_t_s<2><<<720, 512, 0, stream>>>(ws, out, bar + 2);        // t1 | s2
}

// Round 6
// 223.643 us; speedup vs baseline: 1.5476x; 1.5476x over previous
//
#include <hip/hip_runtime.h>
#include <hip/hip_bf16.h>
#include <math.h>

#define B_  512
#define I_  8
#define C_  1152
#define J_  10
#define S_  16
#define K1  9216
#define NKB 288     // sgemm K-blocks (K=9216/32)
#define KBT 16      // tgemm-layout K-blocks of Bt (K=512/32)

typedef short short8 __attribute__((ext_vector_type(8)));
typedef float floatx4 __attribute__((ext_vector_type(4)));

__device__ inline unsigned short f2bf(float f) {
    unsigned int u = __float_as_uint(f);
    return (unsigned short)((u + 0x7FFFu + ((u >> 16) & 1u)) >> 16);
}
__device__ inline unsigned int pack2(float a, float b) {
    __hip_bfloat162 h = __float22bfloat162_rn(float2{a, b});
    return *reinterpret_cast<unsigned int*>(&h);
}

// ---------------------------------------------------------------------------
// PACK: 721 blocks x 512 threads. Verbatim R4 except: zeroes BOTH b_ij
// buffers (2 * C * J floats) for the double-buffered cumulative update.
__global__ __launch_bounds__(512) void k_pack(const float* __restrict__ x,
                                              const float* __restrict__ W,
                                              uint4* __restrict__ Bs,
                                              uint4* __restrict__ Bt,
                                              uint4* __restrict__ Wf,
                                              unsigned short* __restrict__ W2,
                                              float* __restrict__ b_ij) {
    __shared__ float lds[10240];
    const int task = blockIdx.x;
    const int t = threadIdx.x;
    const int w = t >> 6, L = t & 63, quad = L >> 4;

    if (task < 576) {                       // ---- x tile -> Bs + Bt
        const int bt = task / 36, kt = task % 36;
        const int b0 = bt * 32, k0 = kt * 256;
        #pragma unroll
        for (int p = 0; p < 4; p++) {
            int f4 = p * 512 + t;
            int row = f4 >> 6, c4 = (f4 & 63) << 2;
            *(float4*)&lds[row * 260 + c4] =
                *(const float4*)&x[(size_t)(b0 + row) * K1 + k0 + c4];
        }
        __syncthreads();
        #pragma unroll
        for (int p = 0; p < 2; p++) {
            const int bl = p * 16 + (L & 15);
            const float* s = &lds[bl * 260 + w * 32 + quad * 8];
            uint4 o;
            o.x = pack2(s[0], s[1]); o.y = pack2(s[2], s[3]);
            o.z = pack2(s[4], s[5]); o.w = pack2(s[6], s[7]);
            Bs[((size_t)(bt * 2 + p) * NKB + kt * 8 + w) * 64 + L] = o;
        }
        #pragma unroll
        for (int p = 0; p < 2; p++) {
            const int ntl = w * 2 + p;
            const int nl = ntl * 16 + (L & 15);
            float v[8];
            #pragma unroll
            for (int e = 0; e < 8; e++) v[e] = lds[(quad * 8 + e) * 260 + nl];
            uint4 o;
            o.x = pack2(v[0], v[1]); o.y = pack2(v[2], v[3]);
            o.z = pack2(v[4], v[5]); o.w = pack2(v[6], v[7]);
            Bt[((size_t)(kt * 16 + ntl) * KBT + bt) * 64 + L] = o;
        }
    } else if (task < 720) {                // ---- W chunk -> Wf + W2
        const int c0 = (task - 576) * 8;
        #pragma unroll
        for (int p = 0; p < 5; p++) {
            int f4 = p * 512 + t;
            int cc = f4 / 320, off4 = (f4 % 320) << 2;
            *(float4*)&lds[cc * 1280 + off4] =
                *(const float4*)&W[(size_t)(c0 + cc) * 1280 + off4];
        }
        __syncthreads();
        #pragma unroll
        for (int p = 0; p < 3; p++) {
            int o = p * 512 + t;
            if (o < 1280) {
                int j = o >> 7, i = (o >> 4) & 7, m = o & 15;
                int k0w = i * C_ + c0;
                int Lw = m | (((k0w >> 3) & 3) << 4);
                float v[8];
                #pragma unroll
                for (int e = 0; e < 8; e++)
                    v[e] = lds[e * 1280 + j * 128 + m * 8 + i];
                uint4 og;
                og.x = pack2(v[0], v[1]); og.y = pack2(v[2], v[3]);
                og.z = pack2(v[4], v[5]); og.w = pack2(v[6], v[7]);
                Wf[((size_t)j * NKB + (k0w >> 5)) * 64 + Lw] = og;
            }
        }
        #pragma unroll
        for (int p = 0; p < 2; p++) {
            int o = p * 512 + t;
            if (o < 640) {
                int j = o >> 6, i = (o >> 3) & 7, cc = o & 7;
                unsigned int r8[8];
                #pragma unroll
                for (int h = 0; h < 8; h++)
                    r8[h] = pack2(lds[cc * 1280 + j * 128 + (2 * h) * 8 + i],
                                  lds[cc * 1280 + j * 128 + (2 * h + 1) * 8 + i]);
                unsigned short* dst = W2 + ((size_t)(j * 8 + i) * C_ + c0 + cc) * 16;
                *(uint4*)dst       = make_uint4(r8[0], r8[1], r8[2], r8[3]);
                *(uint4*)(dst + 8) = make_uint4(r8[4], r8[5], r8[6], r8[7]);
            }
        }
    } else {                                // ---- zero b_ij (both buffers)
        for (int idx = t; idx < C_ * J_ * 2; idx += 512) b_ij[idx] = 0.0f;
    }
}

// ---------------------------------------------------------------------------
// SGEMM + fold + squash + FUSED b_ij update (per-block P-GEMM, no tgemm
// dispatch). 320 blocks x 512 thr. XCD decode: each XCD owns 8 nt x 5 j.
// Forward sub-phase reads Bs+Wf (~3.8MB/XCD); P sub-phase reads Bt+W2
// (~3.8MB/XCD) — time-separated per block, each L2-fits.
// MODE 0: uniform cnorm=0.1; P adds to bij1 AND bij2 (seeds b1 into both).
// MODE 1: softmax(bij1) fold; P adds to bij2 only.     (b2 = b1 + upd1)
// MODE 2: softmax(bij2) fold; writes out; no P.
// Race note: MODE1 reads bij1 / writes bij2 — no same-dispatch RW conflict.
template<int MODE>
__global__ __launch_bounds__(512) void k_sgemm_bup(
        const short8* __restrict__ Wf, const short8* __restrict__ Bs,
        const short8* __restrict__ Bt, const unsigned short* __restrict__ W2,
        float* __restrict__ bij1, float* __restrict__ bij2,
        float* __restrict__ out) {
    // lds aliasing (all uses time-separated by __syncthreads):
    //   forward: cn = [0,1152) ; parts = [1152,3200)
    //   epilogue: vA (A-fragment v^T, ushort[512]) = [0,256) floats
    //   P phase : bijpart[8][1152] = [256,9472)
    __shared__ float lds[9472];
    const int t = threadIdx.x, w = t >> 6, L = t & 63, quad = L >> 4;
    const int bid = blockIdx.x;
    const int xcd = bid & 7, sl = bid >> 3;     // sl in [0,40)
    const int j  = 5 * (xcd >> 2) + sl % 5;     // 0..9
    const int nt = 8 * (xcd & 3) + sl / 5;      // 16-b tile, 0..31

    const float* bijR = (MODE == 1) ? bij1 : bij2;
    if (MODE) {
        for (int c = t; c < C_; c += 512) {
            float bv[J_], mx = -1e30f;
            #pragma unroll
            for (int jj = 0; jj < J_; jj++) {
                bv[jj] = bijR[c * J_ + jj]; mx = fmaxf(mx, bv[jj]);
            }
            float sum = 0.0f;
            #pragma unroll
            for (int jj = 0; jj < J_; jj++) sum += __expf(bv[jj] - mx);
            lds[c] = __expf(bv[j] - mx) / sum;
        }
    }
    __syncthreads();

    // ---------------- forward GEMM (verbatim R4 body) ----------------------
    const short8* pA = Wf + ((size_t)j * NKB + w * 36) * 64 + L;
    const short8* pB = Bs + ((size_t)nt * NKB + w * 36) * 64 + L;
    floatx4 acc = {0.f, 0.f, 0.f, 0.f};
    if (MODE) {
        #pragma unroll 6
        for (int i = 0; i < 36; i++) {
            short8 a = pA[i * 64];
            const int cb = i * 32 + quad * 8;     // (w*36*32) % 1152 == 0
            float4 cl = *(const float4*)&lds[cb];
            float4 ch = *(const float4*)&lds[cb + 4];
            float cn8[8] = {cl.x, cl.y, cl.z, cl.w, ch.x, ch.y, ch.z, ch.w};
            unsigned int* au = (unsigned int*)&a;
            short8 a2; unsigned int* ao = (unsigned int*)&a2;
            #pragma unroll
            for (int h = 0; h < 4; h++) {
                float f0 = __uint_as_float(au[h] << 16)         * cn8[2 * h];
                float f1 = __uint_as_float(au[h] & 0xffff0000u) * cn8[2 * h + 1];
                ao[h] = pack2(f0, f1);
            }
            acc = __builtin_amdgcn_mfma_f32_16x16x32_bf16(a2, pB[i * 64], acc, 0, 0, 0);
        }
    } else {
        #pragma unroll 6
        for (int i = 0; i < 36; i++)
            acc = __builtin_amdgcn_mfma_f32_16x16x32_bf16(pA[i * 64], pB[i * 64], acc, 0, 0, 0);
    }

    const int col = L & 15, rw = quad << 2;
    float* base = &lds[1152 + w * 256];
    #pragma unroll
    for (int r = 0; r < 4; r++)
        base[(rw + r) * 16 + col] = acc[r];
    __syncthreads();

    // ---------------- epilogue: parallel reduce + squash (R5-verified) -----
    const int h = nt & 1;                    // which 16-half of the 32-b chunk
    unsigned short* vA = (unsigned short*)lds;
    if (t < 256) {
        const int bl = t >> 4, s = t & 15;   // 16-lane group shares bl
        float a = 0.f;
        #pragma unroll
        for (int w8 = 0; w8 < 8; w8++)
            a += lds[1152 + w8 * 256 + s * 16 + bl];
        if (MODE == 0) a *= 0.1f;
        float msq = a * a;
        #pragma unroll
        for (int m = 1; m < 16; m <<= 1) msq += __shfl_xor(msq, m);
        const float scale = msq / ((1.f + msq) * sqrtf(msq));
        const float sv = a * scale;
        if (MODE < 2) {
            // v^T into A-fragment layout: lane Ld = (b32>>3)*16 + s, elem b32&7
            const int b32 = h * 16 + bl;
            vA[(((b32 >> 3) * 16 + s) << 3) | (b32 & 7)] = f2bf(sv);
        } else {
            const int b = nt * 16 + bl;
            out[((size_t)b * J_ + j) * S_ + s] = sv;
        }
    } else if (MODE < 2) {
        // zero the unused K-half of the A fragment
        const int t2 = t - 256, bl2 = t2 >> 4, s2 = t2 & 15;
        const int b32z = (1 - h) * 16 + bl2;
        vA[(((b32z >> 3) * 16 + s2) << 3) | (b32z & 7)] = 0;
    }

    if (MODE == 2) return;

    // ---------------- P phase: b_ij update (fused tgemm) -------------------
    __syncthreads();
    const short8 aF = *(const short8*)&vA[L << 3];   // same v^T frag, all waves
    const int bt2 = nt >> 1;                         // 32-b chunk of Bt
    float* bp = &lds[256 + w * 1152];                // this wave's i = w slice
    const floatx4 zero4 = {0.f, 0.f, 0.f, 0.f};
    #pragma unroll 6
    for (int cc = 0; cc < 72; cc++) {
        const int ktile = w * 72 + cc;               // k/16; i = ktile/72 == w
        short8 bF = Bt[((size_t)ktile * KBT + bt2) * 64 + L];
        floatx4 d = __builtin_amdgcn_mfma_f32_16x16x32_bf16(aF, bF, zero4, 0, 0, 0);
        const int c = cc * 16 + col;
        const unsigned short* wp = W2 + ((size_t)(j * 8 + w) * C_ + c) * 16 + rw;
        uint2 wv = *(const uint2*)wp;                // W[c,j,s=quad*4+r,i=w]
        float p = d[0] * __uint_as_float((unsigned int)wv.x << 16)
                + d[1] * __uint_as_float(wv.x & 0xffff0000u)
                + d[2] * __uint_as_float((unsigned int)wv.y << 16)
                + d[3] * __uint_as_float(wv.y & 0xffff0000u);
        p += __shfl_xor(p, 16);                      // sum the 4 s-quads
        p += __shfl_xor(p, 32);
        if (L < 16) bp[cc * 16 + L] = p;             // distinct c per cc: store
    }
    __syncthreads();
    for (int c = t; c < C_; c += 512) {
        float s8 = 0.f;
        #pragma unroll
        for (int w8 = 0; w8 < 8; w8++) s8 += lds[256 + w8 * 1152 + c];
        const float upd = s8 * (1.0f / 512.f);
        if (MODE == 0) {
            atomicAdd(&bij1[c * J_ + j], upd);       // b1
            atomicAdd(&bij2[c * J_ + j], upd);       // seed b2 = b1
        } else {
            atomicAdd(&bij2[c * J_ + j], upd);       // b2 += upd1
        }
    }
}

// ---------------------------------------------------------------------------
extern "C" void kernel_launch(void* const* d_in, const int* in_sizes, int n_in,
                              void* d_out, int out_size, void* d_ws, size_t ws_size,
                              hipStream_t stream) {
    const float* x = (const float*)d_in[0];   // [512][8][1152]
    const float* W = (const float*)d_in[1];   // [1152][10][16][8]
    float* out = (float*)d_out;               // [512][10][16][1]
    float* ws  = (float*)d_ws;

    float* Bs_f = ws;                    // 2,359,296
    float* Bt_f = Bs_f + 2359296;        // 2,359,296
    float* Wf_f = Bt_f + 2359296;        //   737,280
    float* W2_f = Wf_f + 737280;         //   737,280
    float* bij1 = W2_f + 737280;         //    11,520
    float* bij2 = bij1 + 11520;          //    11,520

    k_pack<<<721, 512, 0, stream>>>(x, W, (uint4*)Bs_f, (uint4*)Bt_f,
                                    (uint4*)Wf_f, (unsigned short*)W2_f, bij1);

    k_sgemm_bup<0><<<320, 512, 0, stream>>>(
        (const short8*)Wf_f, (const short8*)Bs_f, (const short8*)Bt_f,
        (const unsigned short*)W2_f, bij1, bij2, out);
    k_sgemm_bup<1><<<320, 512, 0, stream>>>(
        (const short8*)Wf_f, (const short8*)Bs_f, (const short8*)Bt_f,
        (const unsigned short*)W2_f, bij1, bij2, out);
    k_sgemm_bup<2><<<320, 512, 0, stream>>>(
        (const short8*)Wf_f, (const short8*)Bs_f, (const short8*)Bt_f,
        (const unsigned short*)W2_f, bij1, bij2, out);
}

// Round 7
// 131.092 us; speedup vs baseline: 2.6402x; 1.7060x over previous
//
#include <hip/hip_runtime.h>
#include <hip/hip_bf16.h>
#include <math.h>

#define B_  512
#define I_  8
#define C_  1152
#define J_  10
#define S_  16
#define K1  9216
#define NKB 288     // sgemm K-blocks (K=9216/32)
#define KBT 16      // tgemm K-blocks (K=512/32)

typedef short short8 __attribute__((ext_vector_type(8)));
typedef float floatx4 __attribute__((ext_vector_type(4)));

__device__ inline unsigned short f2bf(float f) {
    unsigned int u = __float_as_uint(f);
    return (unsigned short)((u + 0x7FFFu + ((u >> 16) & 1u)) >> 16);
}
__device__ inline unsigned int pack2(float a, float b) {
    __hip_bfloat162 h = __float22bfloat162_rn(float2{a, b});
    return *reinterpret_cast<unsigned int*>(&h);
}

// ---------------------------------------------------------------------------
// PACK: 721 blocks x 512 threads (reads x once; zeroes b_ij). Verbatim R4.
__global__ __launch_bounds__(512) void k_pack(const float* __restrict__ x,
                                              const float* __restrict__ W,
                                              uint4* __restrict__ Bs,
                                              uint4* __restrict__ Bt,
                                              uint4* __restrict__ Wf,
                                              unsigned short* __restrict__ W2,
                                              float* __restrict__ b_ij) {
    __shared__ float lds[10240];
    const int task = blockIdx.x;
    const int t = threadIdx.x;
    const int w = t >> 6, L = t & 63, quad = L >> 4;

    if (task < 576) {                       // ---- x tile -> Bs + Bt
        const int bt = task / 36, kt = task % 36;
        const int b0 = bt * 32, k0 = kt * 256;
        #pragma unroll
        for (int p = 0; p < 4; p++) {
            int f4 = p * 512 + t;
            int row = f4 >> 6, c4 = (f4 & 63) << 2;
            *(float4*)&lds[row * 260 + c4] =
                *(const float4*)&x[(size_t)(b0 + row) * K1 + k0 + c4];
        }
        __syncthreads();
        #pragma unroll
        for (int p = 0; p < 2; p++) {
            const int bl = p * 16 + (L & 15);
            const float* s = &lds[bl * 260 + w * 32 + quad * 8];
            uint4 o;
            o.x = pack2(s[0], s[1]); o.y = pack2(s[2], s[3]);
            o.z = pack2(s[4], s[5]); o.w = pack2(s[6], s[7]);
            Bs[((size_t)(bt * 2 + p) * NKB + kt * 8 + w) * 64 + L] = o;
        }
        #pragma unroll
        for (int p = 0; p < 2; p++) {
            const int ntl = w * 2 + p;
            const int nl = ntl * 16 + (L & 15);
            float v[8];
            #pragma unroll
            for (int e = 0; e < 8; e++) v[e] = lds[(quad * 8 + e) * 260 + nl];
            uint4 o;
            o.x = pack2(v[0], v[1]); o.y = pack2(v[2], v[3]);
            o.z = pack2(v[4], v[5]); o.w = pack2(v[6], v[7]);
            Bt[((size_t)(kt * 16 + ntl) * KBT + bt) * 64 + L] = o;
        }
    } else if (task < 720) {                // ---- W chunk -> Wf + W2
        const int c0 = (task - 576) * 8;
        #pragma unroll
        for (int p = 0; p < 5; p++) {
            int f4 = p * 512 + t;
            int cc = f4 / 320, off4 = (f4 % 320) << 2;
            *(float4*)&lds[cc * 1280 + off4] =
                *(const float4*)&W[(size_t)(c0 + cc) * 1280 + off4];
        }
        __syncthreads();
        #pragma unroll
        for (int p = 0; p < 3; p++) {
            int o = p * 512 + t;
            if (o < 1280) {
                int j = o >> 7, i = (o >> 4) & 7, m = o & 15;
                int k0w = i * C_ + c0;
                int Lw = m | (((k0w >> 3) & 3) << 4);
                float v[8];
                #pragma unroll
                for (int e = 0; e < 8; e++)
                    v[e] = lds[e * 1280 + j * 128 + m * 8 + i];
                uint4 og;
                og.x = pack2(v[0], v[1]); og.y = pack2(v[2], v[3]);
                og.z = pack2(v[4], v[5]); og.w = pack2(v[6], v[7]);
                Wf[((size_t)j * NKB + (k0w >> 5)) * 64 + Lw] = og;
            }
        }
        #pragma unroll
        for (int p = 0; p < 2; p++) {
            int o = p * 512 + t;
            if (o < 640) {
                int j = o >> 6, i = (o >> 3) & 7, cc = o & 7;
                unsigned int r8[8];
                #pragma unroll
                for (int h = 0; h < 8; h++)
                    r8[h] = pack2(lds[cc * 1280 + j * 128 + (2 * h) * 8 + i],
                                  lds[cc * 1280 + j * 128 + (2 * h + 1) * 8 + i]);
                unsigned short* dst = W2 + ((size_t)(j * 8 + i) * C_ + c0 + cc) * 16;
                *(uint4*)dst       = make_uint4(r8[0], r8[1], r8[2], r8[3]);
                *(uint4*)(dst + 8) = make_uint4(r8[4], r8[5], r8[6], r8[7]);
            }
        }
    } else {                                // ---- zero b_ij
        for (int idx = t; idx < C_ * J_; idx += 512) b_ij[idx] = 0.0f;
    }
}

// ---------------------------------------------------------------------------
// SGEMM + fused fold + reduce + squash. 320 blocks x 512 thr (8-way K-split).
// XCD decode (verified R4): each XCD owns 8 nt x 5 j.
// MLP fix: inner loop restructured to 4 batches of 9 — 18 back-to-back
// global loads in flight per wave (was ~2-6 at unroll 6 / VGPR 64), to lift
// the measured 640 GB/s latency-bound L2-fill rate. launch_bounds(512,4)
// caps VGPR at 128 so 2 blocks/CU remain possible.
// Epilogue: R5-verified parallel reduce (256 thr + 16-lane shfl).
// mode 0: uniform cnorm=0.1; mode 1: softmax fold -> Vf; mode 2: fold -> out.
__global__ __launch_bounds__(512, 4) void k_sgemm_f(const short8* __restrict__ Wf,
                                                    const short8* __restrict__ Bs,
                                                    const float* __restrict__ b_ij,
                                                    unsigned short* __restrict__ Vf,
                                                    float* __restrict__ out,
                                                    int mode) {
    __shared__ float smf[1152 + 2048];   // cn[1152] + parts[8 waves][256]
    const int t = threadIdx.x, w = t >> 6, L = t & 63, quad = L >> 4;
    const int bid = blockIdx.x;
    const int xcd = bid & 7, sl = bid >> 3;     // sl in [0,40)
    const int j  = 5 * (xcd >> 2) + sl % 5;     // 0..9
    const int nt = 8 * (xcd & 3) + sl / 5;      // 16-b tile, 0..31

    if (mode) {
        for (int c = t; c < C_; c += 512) {
            float bv[J_], mx = -1e30f;
            #pragma unroll
            for (int jj = 0; jj < J_; jj++) {
                bv[jj] = b_ij[c * J_ + jj]; mx = fmaxf(mx, bv[jj]);
            }
            float sum = 0.0f;
            #pragma unroll
            for (int jj = 0; jj < J_; jj++) sum += __expf(bv[jj] - mx);
            smf[c] = __expf(bv[j] - mx) / sum;
        }
    }
    __syncthreads();

    const short8* pA = Wf + ((size_t)j * NKB + w * 36) * 64 + L;
    const short8* pB = Bs + ((size_t)nt * NKB + w * 36) * 64 + L;
    floatx4 acc = {0.f, 0.f, 0.f, 0.f};
    if (mode) {
        #pragma unroll
        for (int bb = 0; bb < 4; bb++) {
            short8 av[9], bv9[9];
            #pragma unroll
            for (int u = 0; u < 9; u++) {        // 18 loads in flight
                av[u]  = pA[(bb * 9 + u) * 64];
                bv9[u] = pB[(bb * 9 + u) * 64];
            }
            #pragma unroll
            for (int u = 0; u < 9; u++) {
                const int i = bb * 9 + u;
                const int cb = i * 32 + quad * 8;   // (w*36*32) % 1152 == 0
                float4 cl = *(const float4*)&smf[cb];
                float4 ch = *(const float4*)&smf[cb + 4];
                float cn8[8] = {cl.x, cl.y, cl.z, cl.w, ch.x, ch.y, ch.z, ch.w};
                unsigned int* au = (unsigned int*)&av[u];
                short8 a2; unsigned int* ao = (unsigned int*)&a2;
                #pragma unroll
                for (int h = 0; h < 4; h++) {
                    float f0 = __uint_as_float(au[h] << 16)         * cn8[2 * h];
                    float f1 = __uint_as_float(au[h] & 0xffff0000u) * cn8[2 * h + 1];
                    ao[h] = pack2(f0, f1);
                }
                acc = __builtin_amdgcn_mfma_f32_16x16x32_bf16(a2, bv9[u], acc, 0, 0, 0);
            }
        }
    } else {
        #pragma unroll
        for (int bb = 0; bb < 4; bb++) {
            short8 av[9], bv9[9];
            #pragma unroll
            for (int u = 0; u < 9; u++) {
                av[u]  = pA[(bb * 9 + u) * 64];
                bv9[u] = pB[(bb * 9 + u) * 64];
            }
            #pragma unroll
            for (int u = 0; u < 9; u++)
                acc = __builtin_amdgcn_mfma_f32_16x16x32_bf16(av[u], bv9[u], acc, 0, 0, 0);
        }
    }

    const int col = L & 15, rw = quad << 2;
    float* base = &smf[1152 + w * 256];
    #pragma unroll
    for (int r = 0; r < 4; r++)
        base[(rw + r) * 16 + col] = acc[r];
    __syncthreads();

    if (t < 256) {                       // parallel reduce + squash (R5-verified)
        const int bl = t >> 4, s = t & 15;   // 16-lane group shares bl
        float a = 0.f;
        #pragma unroll
        for (int w8 = 0; w8 < 8; w8++)
            a += smf[1152 + w8 * 256 + s * 16 + bl];
        if (mode == 0) a *= 0.1f;
        float msq = a * a;
        #pragma unroll
        for (int m = 1; m < 16; m <<= 1) msq += __shfl_xor(msq, m);
        const float scale = msq / ((1.f + msq) * sqrtf(msq));
        const float sv = a * scale;
        const int b = nt * 16 + bl;      // global b (0..511)
        if (mode < 2) {
            const int kb = b >> 5, lh = (b >> 3) & 3, e = b & 7;
            Vf[((size_t)(j * KBT + kb) * 64 + (s | (lh << 4))) * 8 + e] = f2bf(sv);
        } else {
            out[((size_t)b * J_ + j) * S_ + s] = sv;
        }
    }
}

// ---------------------------------------------------------------------------
// TGEMM + fused b_ij update, ATOMIC-FREE (verified R4). grid 720 x 512.
// Wave w owns i = w (nt = w*72 + cblk); one block per (c,j) cell => safe
// non-atomic cumulative RMW. MLP fix: 2 batches of 8 (16 loads in flight)
// + W2 load hoisted above the MFMA loop. XCD decode: 9 cblk x 10 j per XCD.
__global__ __launch_bounds__(512, 4) void k_tgemm_bup(const short8* __restrict__ Vf,
                                                      const short8* __restrict__ Bt,
                                                      const unsigned short* __restrict__ W2,
                                                      float* __restrict__ b_ij) {
    __shared__ float red[8][16];
    const int t = threadIdx.x, w = t >> 6, L = t & 63;
    const int bid = blockIdx.x;
    const int xcd = bid & 7, sl = bid >> 3;      // sl in [0,90)
    const int cblk = 9 * xcd + sl / 10;          // 0..71
    const int j    = sl % 10;                    // 0..9
    const int nt   = w * 72 + cblk;              // wave w handles i = w
    const short8* pA = Vf + (size_t)j * KBT * 64 + L;
    const short8* pB = Bt + (size_t)nt * KBT * 64 + L;

    const int col = L & 15, rw = (L >> 4) << 2;
    const int c = cblk * 16 + col;
    const unsigned short* wp = W2 + ((size_t)(j * 8 + w) * C_ + c) * 16 + rw;
    uint2 wv = *(const uint2*)wp;                // hoisted: independent load

    floatx4 a = {0.f, 0.f, 0.f, 0.f};
    #pragma unroll
    for (int bb = 0; bb < 2; bb++) {
        short8 av[8], bv[8];
        #pragma unroll
        for (int u = 0; u < 8; u++) {            // 16 loads in flight
            av[u] = pA[(bb * 8 + u) * 64];
            bv[u] = pB[(bb * 8 + u) * 64];
        }
        #pragma unroll
        for (int u = 0; u < 8; u++)
            a = __builtin_amdgcn_mfma_f32_16x16x32_bf16(av[u], bv[u], a, 0, 0, 0);
    }

    float p = a[0] * __uint_as_float((unsigned int)wv.x << 16)
            + a[1] * __uint_as_float(wv.x & 0xffff0000u)
            + a[2] * __uint_as_float((unsigned int)wv.y << 16)
            + a[3] * __uint_as_float(wv.y & 0xffff0000u);
    p += __shfl_xor(p, 16);              // sum s-quads across the wave
    p += __shfl_xor(p, 32);
    if ((L >> 4) == 0) red[w][col] = p;  // per-wave partial (i = w)
    __syncthreads();
    if (t < 16) {
        float acc = 0.f;
        #pragma unroll
        for (int w8 = 0; w8 < 8; w8++) acc += red[w8][t];
        const size_t idx = (size_t)(cblk * 16 + t) * J_ + j;
        b_ij[idx] += acc * (1.0f / 512.f);   // CUMULATIVE (ref semantics)
    }
}

// ---------------------------------------------------------------------------
extern "C" void kernel_launch(void* const* d_in, const int* in_sizes, int n_in,
                              void* d_out, int out_size, void* d_ws, size_t ws_size,
                              hipStream_t stream) {
    const float* x = (const float*)d_in[0];   // [512][8][1152]
    const float* W = (const float*)d_in[1];   // [1152][10][16][8]
    float* out = (float*)d_out;               // [512][10][16][1]
    float* ws  = (float*)d_ws;

    float* Bs_f = ws;                    // 2,359,296
    float* Bt_f = Bs_f + 2359296;        // 2,359,296
    float* Wf_f = Bt_f + 2359296;        //   737,280
    float* W2_f = Wf_f + 737280;         //   737,280
    float* Vf_f = W2_f + 737280;         //    40,960
    float* bij  = Vf_f + 40960;          //    11,520
    // total ~25 MB

    k_pack<<<721, 512, 0, stream>>>(x, W, (uint4*)Bs_f, (uint4*)Bt_f,
                                    (uint4*)Wf_f, (unsigned short*)W2_f, bij);

    k_sgemm_f<<<320, 512, 0, stream>>>(
        (const short8*)Wf_f, (const short8*)Bs_f, bij,
        (unsigned short*)Vf_f, out, 0);
    k_tgemm_bup<<<720, 512, 0, stream>>>(
        (const short8*)Vf_f, (const short8*)Bt_f, (const unsigned short*)W2_f, bij);

    k_sgemm_f<<<320, 512, 0, stream>>>(
        (const short8*)Wf_f, (const short8*)Bs_f, bij,
        (unsigned short*)Vf_f, out, 1);
    k_tgemm_bup<<<720, 512, 0, stream>>>(
        (const short8*)Vf_f, (const short8*)Bt_f, (const unsigned short*)W2_f, bij);

    k_sgemm_f<<<320, 512, 0, stream>>>(
        (const short8*)Wf_f, (const short8*)Bs_f, bij,
        (unsigned short*)Vf_f, out, 2);
}